// Round 19
// baseline (221.958 us; speedup 1.0000x reference)
//
#include <hip/hip_runtime.h>

#define LR 0.01f

// Problem constants (from reference setup_inputs): B=4, S=2048, D=1024, Ds=256
constexpr int Bc  = 4;
constexpr int Sc  = 2048;
constexpr int Dc  = 1024;
constexpr int Dsc = 256;

typedef unsigned short u16;
typedef __attribute__((ext_vector_type(8))) short bf16x8;
typedef __attribute__((ext_vector_type(4))) float f32x4;

__device__ __forceinline__ u16 f2bf(float f) {
  unsigned u = __float_as_uint(f);
  unsigned r = (u + 0x7fff + ((u >> 16) & 1)) >> 16;  // round-to-nearest-even
  return (u16)r;
}
__device__ __forceinline__ float bf2f(u16 h) {
  return __uint_as_float((unsigned)h << 16);
}

__device__ __forceinline__ void async_cp16(const void* g, void* l) {
  __builtin_amdgcn_global_load_lds(
      (const __attribute__((address_space(1))) unsigned int*)g,
      (__attribute__((address_space(3))) unsigned int*)l, 16, 0, 0);
}

// ---------------------------------------------------------------------------
// v20: scan repartitioned to 8 waves/SIMD (1024-thread blocks, 2 cols x
// 8 row-eighths, 4 rows/wave; two-round acc merge keeps LDS at 78KB so 2
// blocks/CU = 32 waves/CU). v19 scan was issue-bound at 65% VALUBusy with
// only 4 waves/SIMD. GEMMs/casts/gram unchanged (verified, absmax 16).
// ---------------------------------------------------------------------------

// Elementwise fp32 -> (hi, lo) bf16 split.
__global__ __launch_bounds__(256) void cast_split(const float* __restrict__ in,
                                                  u16* __restrict__ hi,
                                                  u16* __restrict__ lo) {
  int i = (blockIdx.x * 256 + threadIdx.x) * 4;
  float4 v = *(const float4*)&in[i];
  ushort4 h, l;
  h.x = f2bf(v.x); l.x = f2bf(v.x - bf2f(h.x));
  h.y = f2bf(v.y); l.y = f2bf(v.y - bf2f(h.y));
  h.z = f2bf(v.z); l.z = f2bf(v.z - bf2f(h.z));
  h.w = f2bf(v.w); l.w = f2bf(v.w - bf2f(h.w));
  *(ushort4*)&hi[i] = h;
  *(ushort4*)&lo[i] = l;
}

// W [K][N] fp32 -> WT [N][K] bf16 single (for Wu).
__global__ __launch_bounds__(256) void castT_bf16(const float* __restrict__ W,
                                                  u16* __restrict__ WT,
                                                  int K, int N) {
  __shared__ float t[32][33];
  const int bk = blockIdx.x * 32, bn = blockIdx.y * 32;
  const int tx = threadIdx.x & 31, ty = threadIdx.x >> 5;
  for (int r = ty; r < 32; r += 8) t[r][tx] = W[(size_t)(bk + r) * N + bn + tx];
  __syncthreads();
  for (int r = ty; r < 32; r += 8)
    WT[(size_t)(bn + r) * K + bk + tx] = f2bf(t[tx][r]);
}

// W [K][N] fp32 -> WT hi/lo [N][K] bf16 pair (for Wd).
__global__ __launch_bounds__(256) void castT_split(const float* __restrict__ W,
                                                   u16* __restrict__ WThi,
                                                   u16* __restrict__ WTlo,
                                                   int K, int N) {
  __shared__ float t[32][33];
  const int bk = blockIdx.x * 32, bn = blockIdx.y * 32;
  const int tx = threadIdx.x & 31, ty = threadIdx.x >> 5;
  for (int r = ty; r < 32; r += 8) t[r][tx] = W[(size_t)(bk + r) * N + bn + tx];
  __syncthreads();
  for (int r = ty; r < 32; r += 8) {
    float v = t[tx][r];
    u16 h = f2bf(v);
    WThi[(size_t)(bn + r) * K + bk + tx] = h;
    WTlo[(size_t)(bn + r) * K + bk + tx] = f2bf(v - bf2f(h));
  }
}

// ---------------------------------------------------------------------------
// 3-term split MFMA GEMM (v19, verified): C = (Ah+Al)@(Bh+Bl) + bias.
// ---------------------------------------------------------------------------
__global__ __launch_bounds__(256) void gemm_bf16_split3(
    const u16* __restrict__ Ahi, const u16* __restrict__ Alo,
    const u16* __restrict__ BThi, const u16* __restrict__ BTlo,
    const float* __restrict__ bias, float* __restrict__ C,
    int M, int N, int K) {
  constexpr int BK = 32;
  __shared__ u16 sAh[2][64 * BK];
  __shared__ u16 sAl[2][64 * BK];
  __shared__ u16 sBh[2][64 * BK];
  __shared__ u16 sBl[2][64 * BK];

  const int wv = threadIdx.x >> 6, lane = threadIdx.x & 63;
  const int bm = blockIdx.x * 64, bn = blockIdx.y * 64;
  const int qm = (wv >> 1) * 32, qn = (wv & 1) * 32;
  const int lr = lane & 15, lk = lane >> 4;

  const int srow = lane >> 2;
  const int skp  = (lane & 3) * 8;
  const int NKS = K / BK;

#define GSTAGE(BUF, KS)                                                   \
  {                                                                       \
    async_cp16(Ahi + (size_t)(bm + wv * 16 + srow) * K + (KS)*BK + skp,   \
               &sAh[BUF][wv * 512]);                                      \
    async_cp16(Alo + (size_t)(bm + wv * 16 + srow) * K + (KS)*BK + skp,   \
               &sAl[BUF][wv * 512]);                                      \
    async_cp16(BThi + (size_t)(bn + wv * 16 + srow) * K + (KS)*BK + skp,  \
               &sBh[BUF][wv * 512]);                                      \
    async_cp16(BTlo + (size_t)(bn + wv * 16 + srow) * K + (KS)*BK + skp,  \
               &sBl[BUF][wv * 512]);                                      \
  }

  f32x4 acc00 = {0.f, 0.f, 0.f, 0.f}, acc01 = {0.f, 0.f, 0.f, 0.f};
  f32x4 acc10 = {0.f, 0.f, 0.f, 0.f}, acc11 = {0.f, 0.f, 0.f, 0.f};

  GSTAGE(0, 0);
  GSTAGE(1, 1);
  asm volatile("s_waitcnt vmcnt(4)" ::: "memory");
  __builtin_amdgcn_s_barrier();

  for (int ks = 0; ks < NKS; ++ks) {
    const int cb = ks & 1;
    bf16x8 ah0 = *(const bf16x8*)&sAh[cb][(qm + lr) * BK + lk * 8];
    bf16x8 ah1 = *(const bf16x8*)&sAh[cb][(qm + 16 + lr) * BK + lk * 8];
    bf16x8 al0 = *(const bf16x8*)&sAl[cb][(qm + lr) * BK + lk * 8];
    bf16x8 al1 = *(const bf16x8*)&sAl[cb][(qm + 16 + lr) * BK + lk * 8];
    bf16x8 bh0 = *(const bf16x8*)&sBh[cb][(qn + lr) * BK + lk * 8];
    bf16x8 bh1 = *(const bf16x8*)&sBh[cb][(qn + 16 + lr) * BK + lk * 8];
    bf16x8 bl0 = *(const bf16x8*)&sBl[cb][(qn + lr) * BK + lk * 8];
    bf16x8 bl1 = *(const bf16x8*)&sBl[cb][(qn + 16 + lr) * BK + lk * 8];
    acc00 = __builtin_amdgcn_mfma_f32_16x16x32_bf16(ah0, bh0, acc00, 0, 0, 0);
    acc01 = __builtin_amdgcn_mfma_f32_16x16x32_bf16(ah0, bh1, acc01, 0, 0, 0);
    acc10 = __builtin_amdgcn_mfma_f32_16x16x32_bf16(ah1, bh0, acc10, 0, 0, 0);
    acc11 = __builtin_amdgcn_mfma_f32_16x16x32_bf16(ah1, bh1, acc11, 0, 0, 0);
    acc00 = __builtin_amdgcn_mfma_f32_16x16x32_bf16(ah0, bl0, acc00, 0, 0, 0);
    acc01 = __builtin_amdgcn_mfma_f32_16x16x32_bf16(ah0, bl1, acc01, 0, 0, 0);
    acc10 = __builtin_amdgcn_mfma_f32_16x16x32_bf16(ah1, bl0, acc10, 0, 0, 0);
    acc11 = __builtin_amdgcn_mfma_f32_16x16x32_bf16(ah1, bl1, acc11, 0, 0, 0);
    acc00 = __builtin_amdgcn_mfma_f32_16x16x32_bf16(al0, bh0, acc00, 0, 0, 0);
    acc01 = __builtin_amdgcn_mfma_f32_16x16x32_bf16(al0, bh1, acc01, 0, 0, 0);
    acc10 = __builtin_amdgcn_mfma_f32_16x16x32_bf16(al1, bh0, acc10, 0, 0, 0);
    acc11 = __builtin_amdgcn_mfma_f32_16x16x32_bf16(al1, bh1, acc11, 0, 0, 0);
    __builtin_amdgcn_s_barrier();
    if (ks + 2 < NKS) {
      GSTAGE(cb, ks + 2);
      asm volatile("s_waitcnt vmcnt(4)" ::: "memory");
    } else {
      asm volatile("s_waitcnt vmcnt(0)" ::: "memory");
    }
    __builtin_amdgcn_s_barrier();
  }

#define WRT(ACC, AR, BC)                                                 \
  {                                                                      \
    _Pragma("unroll")                                                    \
    for (int r = 0; r < 4; ++r) {                                        \
      int row = bm + qm + (AR) + lk * 4 + r;                             \
      int col = bn + qn + (BC) + lr;                                     \
      C[(size_t)row * N + col] = ACC[r] + bias[col];                     \
    }                                                                    \
  }
  WRT(acc00, 0, 0) WRT(acc01, 0, 16) WRT(acc10, 16, 0) WRT(acc11, 16, 16)
#undef WRT
#undef GSTAGE
}

// ---------------------------------------------------------------------------
// bf16 MFMA GEMM with HI/LO-split A only (v18, verified).
// ---------------------------------------------------------------------------
__global__ __launch_bounds__(256) void gemm_bf16_split(
    const u16* __restrict__ Ahi, const u16* __restrict__ Alo,
    const u16* __restrict__ BT, const float* __restrict__ bias,
    const float* __restrict__ resid, float* __restrict__ C,
    int M, int N, int K) {
  constexpr int BK = 32;
  __shared__ u16 sAh[2][64 * BK];
  __shared__ u16 sAl[2][64 * BK];
  __shared__ u16 sB[2][64 * BK];

  const int wv = threadIdx.x >> 6, lane = threadIdx.x & 63;
  const int bm = blockIdx.x * 64, bn = blockIdx.y * 64;
  const int qm = (wv >> 1) * 32, qn = (wv & 1) * 32;
  const int lr = lane & 15, lk = lane >> 4;

  const int srow = lane >> 2;
  const int skp  = (lane & 3) * 8;
  const int NKS = K / BK;

#define GSTAGE(BUF, KS)                                                   \
  {                                                                       \
    async_cp16(Ahi + (size_t)(bm + wv * 16 + srow) * K + (KS)*BK + skp,   \
               &sAh[BUF][wv * 512]);                                      \
    async_cp16(Alo + (size_t)(bm + wv * 16 + srow) * K + (KS)*BK + skp,   \
               &sAl[BUF][wv * 512]);                                      \
    async_cp16(BT + (size_t)(bn + wv * 16 + srow) * K + (KS)*BK + skp,    \
               &sB[BUF][wv * 512]);                                       \
  }

  f32x4 acc00 = {0.f, 0.f, 0.f, 0.f}, acc01 = {0.f, 0.f, 0.f, 0.f};
  f32x4 acc10 = {0.f, 0.f, 0.f, 0.f}, acc11 = {0.f, 0.f, 0.f, 0.f};

  GSTAGE(0, 0);
  GSTAGE(1, 1);
  asm volatile("s_waitcnt vmcnt(3)" ::: "memory");
  __builtin_amdgcn_s_barrier();

  for (int ks = 0; ks < NKS; ++ks) {
    const int cb = ks & 1;
    bf16x8 ah0 = *(const bf16x8*)&sAh[cb][(qm + lr) * BK + lk * 8];
    bf16x8 ah1 = *(const bf16x8*)&sAh[cb][(qm + 16 + lr) * BK + lk * 8];
    bf16x8 al0 = *(const bf16x8*)&sAl[cb][(qm + lr) * BK + lk * 8];
    bf16x8 al1 = *(const bf16x8*)&sAl[cb][(qm + 16 + lr) * BK + lk * 8];
    bf16x8 b0  = *(const bf16x8*)&sB[cb][(qn + lr) * BK + lk * 8];
    bf16x8 b1  = *(const bf16x8*)&sB[cb][(qn + 16 + lr) * BK + lk * 8];
    acc00 = __builtin_amdgcn_mfma_f32_16x16x32_bf16(ah0, b0, acc00, 0, 0, 0);
    acc01 = __builtin_amdgcn_mfma_f32_16x16x32_bf16(ah0, b1, acc01, 0, 0, 0);
    acc10 = __builtin_amdgcn_mfma_f32_16x16x32_bf16(ah1, b0, acc10, 0, 0, 0);
    acc11 = __builtin_amdgcn_mfma_f32_16x16x32_bf16(ah1, b1, acc11, 0, 0, 0);
    acc00 = __builtin_amdgcn_mfma_f32_16x16x32_bf16(al0, b0, acc00, 0, 0, 0);
    acc01 = __builtin_amdgcn_mfma_f32_16x16x32_bf16(al0, b1, acc01, 0, 0, 0);
    acc10 = __builtin_amdgcn_mfma_f32_16x16x32_bf16(al1, b0, acc10, 0, 0, 0);
    acc11 = __builtin_amdgcn_mfma_f32_16x16x32_bf16(al1, b1, acc11, 0, 0, 0);
    __builtin_amdgcn_s_barrier();
    if (ks + 2 < NKS) {
      GSTAGE(cb, ks + 2);
      asm volatile("s_waitcnt vmcnt(3)" ::: "memory");
    } else {
      asm volatile("s_waitcnt vmcnt(0)" ::: "memory");
    }
    __builtin_amdgcn_s_barrier();
  }

#define WRT(ACC, AR, BC)                                                 \
  {                                                                      \
    _Pragma("unroll")                                                    \
    for (int r = 0; r < 4; ++r) {                                        \
      int row = bm + qm + (AR) + lk * 4 + r;                             \
      int col = bn + qn + (BC) + lr;                                     \
      float v = ACC[r] + bias[col];                                      \
      if (resid) v += resid[(size_t)row * N + col];                      \
      C[(size_t)row * N + col] = v;                                      \
    }                                                                    \
  }
  WRT(acc00, 0, 0) WRT(acc01, 0, 16) WRT(acc10, 16, 0) WRT(acc11, 16, 16)
#undef WRT
#undef GSTAGE
}

// ---------------------------------------------------------------------------
// Scan support (unchanged).
// ---------------------------------------------------------------------------

template <int CTRL, int RM>
__device__ __forceinline__ float dpp_sum(float v) {
  int moved = __builtin_amdgcn_update_dpp(0, __float_as_int(v), CTRL, RM, 0xF, false);
  return v + __int_as_float(moved);
}

__device__ __forceinline__ float rdlane(float v, int l) {
  return __int_as_float(__builtin_amdgcn_readlane(__float_as_int(v), l));
}

constexpr int RCH = 32;        // rows per chunk
constexpr int NCH = Sc / RCH;  // 64 chunks

// MTg[bc][s*32+t] = M[t][s], M = (I + L)^{-1}, L[t][s] = LR*dot(f_t,f_s) s<t
__global__ __launch_bounds__(256) void gram_inv(const float* __restrict__ feat,
                                                float* __restrict__ MTg) {
  const int bc = blockIdx.x;  // 0..B*NCH-1
  __shared__ float Fl[32 * 260];
  __shared__ float Gl[32 * 32];
  __shared__ float Ml[32 * 32];
  const float* src = feat + (size_t)bc * RCH * Dsc;
  for (int i = threadIdx.x; i < 32 * 256; i += 256) {
    int r = i >> 8, cc = i & 255;
    Fl[r * 260 + cc] = src[i];
  }
  __syncthreads();
#pragma unroll
  for (int k2 = 0; k2 < 4; ++k2) {
    int idx = threadIdx.x + (k2 << 8);
    int t = idx >> 5, s = idx & 31;
    float sum = 0.f;
    if (s < t) {
      const float4* ft = (const float4*)&Fl[t * 260];
      const float4* fs = (const float4*)&Fl[s * 260];
#pragma unroll
      for (int i = 0; i < 64; ++i) {
        float4 a = ft[i], b = fs[i];
        sum = fmaf(a.x, b.x, sum); sum = fmaf(a.y, b.y, sum);
        sum = fmaf(a.z, b.z, sum); sum = fmaf(a.w, b.w, sum);
      }
      sum *= LR;
    }
    Gl[idx] = sum;
  }
  __syncthreads();
  if (threadIdx.x < 32) {
    const int s = threadIdx.x;
    for (int t = 0; t < 32; ++t) {
      float sum = 0.f;
      for (int u = 0; u < t; ++u)
        sum = fmaf(Gl[t * 32 + u], Ml[u * 32 + s], sum);
      Ml[t * 32 + s] = ((t == s) ? 1.f : 0.f) - sum;
    }
  }
  __syncthreads();
  float* dst = MTg + (size_t)bc * 1024;
#pragma unroll
  for (int k2 = 0; k2 < 4; ++k2) {
    int idx = threadIdx.x + (k2 << 8);
    int s = idx >> 5, t = idx & 31;
    dst[idx] = Ml[t * 32 + s];  // transposed store
  }
}

__device__ __forceinline__ void async_copy16f(const float* g, float* l) {
  __builtin_amdgcn_global_load_lds(
      (const __attribute__((address_space(1))) unsigned int*)g,
      (__attribute__((address_space(3))) unsigned int*)l, 16, 0, 0);
}

// Per-wave local rows 0..3 (eighth = 4 rows).
#define QROWS(X) X(0) X(1) X(2) X(3)

// ---------------------------------------------------------------------------
// v20 scan: 512 blocks x 1024 threads = 16 waves (2 cols x 8 eighths);
// LDS 78KB -> 2 blocks/CU -> 32 waves/CU = 8/SIMD. Two-round acc merge.
// ---------------------------------------------------------------------------
__global__ __launch_bounds__(1024, 8) void ttt_scan(
    const float* __restrict__ feat, const float* __restrict__ MTg,
    u16* __restrict__ predsHi, u16* __restrict__ predsLo) {
  const int lane = threadIdx.x & 63;
  const int wv   = threadIdx.x >> 6;   // 0..15
  const int lm   = lane & 31;
  const int cl   = wv & 1;             // column within block
  const int qr   = wv >> 1;            // row eighth (4 rows each), 0..7
  const int rbase = qr << 2;

  // XCD-locality swizzle for 512 blocks (bijective).
  const int bi  = blockIdx.x;                    // 0..511
  const int xcd = bi & 7;
  const int b   = xcd >> 1;                      // 0..3
  const int q   = ((bi >> 3) << 1) | (xcd & 1);  // 0..127 col-pair within b
  const int j   = (q << 1) | cl;                 // 0..255

  __shared__ float  ldsF[2][RCH * Dsc];  // 64 KB
  __shared__ float  ldsE[2][8][64];      // 4 KB  e-partial exchange
  __shared__ float4 ldsA[2][4][64];      // 8 KB  two-round acc merge
  __shared__ float4 ldsW[2][64];         // 2 KB  w' publish
  // total 78 KB -> 2 blocks/CU = 32 waves/CU = 8/SIMD

  const float* fb0 = feat + (size_t)b * Sc * Dsc;
  const float* Mg  = MTg + (size_t)b * NCH * 1024;
  u16* pbh = predsHi + (size_t)b * Sc * Dsc + j;
  u16* pbl = predsLo + (size_t)b * Sc * Dsc + j;

// 2 async ops per wave per stage (32 rows / 16 waves).
#define STAGE(BUF, C0)                                                     \
  {                                                                        \
    _Pragma("unroll")                                                      \
    for (int r_ = 0; r_ < 2; ++r_) {                                       \
      const int row_ = (wv << 1) | r_;                                     \
      async_copy16f(fb0 + (size_t)((C0) * RCH + row_) * Dsc + (lane << 2), \
                    &ldsF[BUF][row_ * Dsc]);                               \
    }                                                                      \
  }

// M prefetch for chunk C1 (4 plain global loads, L2-resident).
#define LOADM(C1)                                             \
  {                                                           \
    const float* mp_ = Mg + (size_t)(C1) * 1024 + lm;         \
    Mn0 = mp_[(rbase + 0) * 32]; Mn1 = mp_[(rbase + 1) * 32]; \
    Mn2 = mp_[(rbase + 2) * 32]; Mn3 = mp_[(rbase + 3) * 32]; \
  }

#define DECLF(R) float4 F4_##R;
#define DECLD(R) float dsc_##R;

#define LOADF(R) F4_##R = *(const float4*)&pF2[(R) * 256 + (lane << 2)];

// P0 with w' state: d = f . w' (no FJ).
#define P0C(R)                                                                 \
  {                                                                            \
    float dd = fmaf(F4_##R.y, w4y, F4_##R.x * w4x) +                           \
               fmaf(F4_##R.w, w4w, F4_##R.z * w4z);                            \
    dd = dpp_sum<0x111, 0xF>(dd);                                              \
    dd = dpp_sum<0x112, 0xF>(dd);                                              \
    dd = dpp_sum<0x114, 0xF>(dd);                                              \
    dd = dpp_sum<0x118, 0xF>(dd);                                              \
    dd = dpp_sum<0x142, 0xA>(dd);                                              \
    dd = dpp_sum<0x143, 0xC>(dd);                                              \
    dsc_##R = rdlane(dd, 63);                                                  \
  }

// Matvec over OWN-eighth s (M in registers, d uniform).
#define MV(R) e_p = fmaf(Mc##R, dsc_##R, e_p);

// acc += e_t * f_t over own rows.
#define ACCT(R)                                    \
  {                                                \
    float et_ = rdlane(v_e, rbase + (R));          \
    accx = fmaf(et_, F4_##R.x, accx);              \
    accy = fmaf(et_, F4_##R.y, accy);              \
    accz = fmaf(et_, F4_##R.z, accz);              \
    accw = fmaf(et_, F4_##R.w, accw);              \
  }

  float Mc0, Mc1, Mc2, Mc3;
  float Mn0, Mn1, Mn2, Mn3;

  // Prologue: stage chunks 0,1 (4 ops) + M for chunk 0 (4 loads).
  STAGE(0, 0);
  STAGE(1, 1);
  LOADM(0);
  Mc0 = Mn0; Mc1 = Mn1; Mc2 = Mn2; Mc3 = Mn3;
  asm volatile("s_waitcnt vmcnt(6)" ::: "memory");  // stage-0 (oldest 2) done
  __builtin_amdgcn_s_barrier();
  __builtin_amdgcn_sched_barrier(0);

  // w' = w - e_j state: init -e_j (component j&3 of lane j>>2).
  const int jl4 = j >> 2, jc = j & 3;
  float w4x = (lane == jl4 && jc == 0) ? -1.f : 0.f;
  float w4y = (lane == jl4 && jc == 1) ? -1.f : 0.f;
  float w4z = (lane == jl4 && jc == 2) ? -1.f : 0.f;
  float w4w = (lane == jl4 && jc == 3) ? -1.f : 0.f;

#pragma unroll 1
  for (int c = 0; c < NCH; ++c) {
    const int cb = c & 1;
    const float* pF  = &ldsF[cb][0];
    const float* pF2 = pF + (rbase << 8);   // + rbase*256

    // M prefetch for next chunk (latency spans the whole chunk).
    if (c + 1 < NCH) LOADM(c + 1);

    QROWS(DECLF)
    QROWS(DECLD)
    float e_p = 0.f;
    float accx = 0.f, accy = 0.f, accz = 0.f, accw = 0.f;

    // FJ column only in the output wave (32-way conflict, 1 instr).
    float v_fjcol = 0.f;
    if (qr == 0) v_fjcol = pF[lm * 256 + j];

    // Phase 1: 4 own rows; loads grouped ahead of reduces.
    QROWS(LOADF)
    __builtin_amdgcn_sched_barrier(0);
    QROWS(P0C)

    // Phase 2: partial e over own-eighth s (registers only).
    MV(0) MV(1) MV(2) MV(3)

    // e exchange across eighths (fixed order -> deterministic).
    ldsE[cl][qr][lane] = e_p;
    __builtin_amdgcn_s_barrier();                 // bE
    float v_e = ((ldsE[cl][0][lane] + ldsE[cl][1][lane]) +
                 (ldsE[cl][2][lane] + ldsE[cl][3][lane])) +
                ((ldsE[cl][4][lane] + ldsE[cl][5][lane]) +
                 (ldsE[cl][6][lane] + ldsE[cl][7][lane]));

    // Phase 3: preds (single writer: qr==0).
    if (qr == 0 && lane < 32) {
      float v = v_e + v_fjcol;
      u16 hi = f2bf(v);
      u16 lo = f2bf(v - bf2f(hi));
      pbh[(size_t)(c * RCH + lane) * Dsc] = hi;
      pbl[(size_t)(c * RCH + lane) * Dsc] = lo;
    }

    // Phase 4: partial acc over own rows.
    QROWS(ACCT)

    // Two-round acc merge (LDS budget: [2][4][64] float4 only).
    // Round 1: qr>=4 publish into slots 0..3.
    if (qr >= 4) ldsA[cl][qr - 4][lane] = make_float4(accx, accy, accz, accw);
    __builtin_amdgcn_s_barrier();                 // bA1
    if (qr < 4) {
      float4 o = ldsA[cl][qr][lane];
      accx += o.x; accy += o.y; accz += o.z; accw += o.w;
      // Round 2: qr 1..3 publish merged partials (own slot; single R/W wave).
      if (qr != 0) ldsA[cl][qr][lane] = make_float4(accx, accy, accz, accw);
    }
    __builtin_amdgcn_s_barrier();                 // bA2
    if (qr == 0) {
      float4 a1 = ldsA[cl][1][lane], a2 = ldsA[cl][2][lane],
             a3 = ldsA[cl][3][lane];
      accx += a1.x + a2.x + a3.x; accy += a1.y + a2.y + a3.y;
      accz += a1.z + a2.z + a3.z; accw += a1.w + a2.w + a3.w;
      w4x = fmaf(-LR, accx, w4x); w4y = fmaf(-LR, accy, w4y);
      w4z = fmaf(-LR, accz, w4z); w4w = fmaf(-LR, accw, w4w);
      ldsW[cl][lane] = make_float4(w4x, w4y, w4z, w4w);
    }

    // Handoff: stage c+2 over cb; counted vmcnt(6) = 4 Mn + 2 stage-c+2 in
    // flight -> stage-c+1 (older) done.
    if (c + 2 < NCH) {
      STAGE(cb, c + 2);
      asm volatile("s_waitcnt vmcnt(6)" ::: "memory");
    } else {
      asm volatile("s_waitcnt vmcnt(0)" ::: "memory");
    }
    __builtin_amdgcn_s_barrier();                 // bFinal (w' + stage vis)
    if (qr != 0) {
      float4 wp = ldsW[cl][lane];
      w4x = wp.x; w4y = wp.y; w4z = wp.z; w4w = wp.w;
    }
    Mc0 = Mn0; Mc1 = Mn1; Mc2 = Mn2; Mc3 = Mn3;
    __builtin_amdgcn_sched_barrier(0);
  }
#undef ACCT
#undef MV
#undef P0C
#undef LOADF
#undef DECLD
#undef DECLF
#undef LOADM
#undef STAGE
}

extern "C" void kernel_launch(void* const* d_in, const int* in_sizes, int n_in,
                              void* d_out, int out_size, void* d_ws, size_t ws_size,
                              hipStream_t stream) {
  const float* x  = (const float*)d_in[0];  // (B,S,D)
  const float* Wd = (const float*)d_in[1];  // (D,Ds)
  const float* bd = (const float*)d_in[2];  // (Ds)
  const float* Wu = (const float*)d_in[3];  // (Ds,D)
  const float* bu = (const float*)d_in[4];  // (D)
  float* out = (float*)d_out;               // (B,S,D)

  const int M = Bc * Sc;  // 8192

  // Workspace layout (~43.5 MB with aliasing):
  u16*   xhi   = (u16*)d_ws;                         // 16.8 MB
  u16*   xlo   = xhi + (size_t)M * Dc;               // 16.8 MB
  float* feat  = (float*)(xlo + (size_t)M * Dc);     // 8.4 MB
  u16*   wdThi = (u16*)(feat + (size_t)M * Dsc);     // 0.5 MB [Ds][D]
  u16*   wdTlo = wdThi + (size_t)Dc * Dsc;           // 0.5 MB
  u16*   wuT   = wdTlo + (size_t)Dc * Dsc;           // 0.5 MB [D][Ds]
  // Aliased into xhi's region (xhi/xlo dead after gemm1; stream-ordered):
  float* MTg     = (float*)xhi;                      // 1 MB
  u16*   predsHi = (u16*)(MTg + (size_t)Bc * NCH * 1024);  // 4.2 MB
  u16*   predsLo = predsHi + (size_t)Bc * Sc * Dsc;        // 4.2 MB

  // Casts: x -> hi/lo bf16; Wd -> transposed hi/lo; Wu -> transposed bf16.
  cast_split<<<dim3(M * Dc / 1024), dim3(256), 0, stream>>>(x, xhi, xlo);
  castT_split<<<dim3(Dc / 32, Dsc / 32), dim3(256), 0, stream>>>(
      Wd, wdThi, wdTlo, Dc, Dsc);
  castT_bf16<<<dim3(Dsc / 32, Dc / 32), dim3(256), 0, stream>>>(
      Wu, wuT, Dsc, Dc);

  // feat = (xhi+xlo) @ (wdhi+wdlo) + b_down  (3-term MFMA; rel err ~1e-5)
  gemm_bf16_split3<<<dim3(M / 64, Dsc / 64), dim3(256), 0, stream>>>(
      xhi, xlo, wdThi, wdTlo, bd, feat, M, Dsc, Dc);

  // per-chunk M = (I+L)^{-1} (fp32, parallel)
  gram_inv<<<dim3(Bc * NCH), dim3(256), 0, stream>>>(feat, MTg);

  // chunked scan -> preds hi/lo bf16 (512 blocks x 16 waves; 8 waves/SIMD)
  ttt_scan<<<dim3(Bc * Dsc / 2), dim3(1024), 0, stream>>>(
      feat, MTg, predsHi, predsLo);

  // out = (predsHi+predsLo) @ W_up + b_up + x  (MFMA bf16)
  gemm_bf16_split<<<dim3(M / 64, Dc / 64), dim3(256), 0, stream>>>(
      predsHi, predsLo, wuT, bu, x, out, M, Dc, Dsc);
}

// Round 20
// 212.593 us; speedup vs baseline: 1.0441x; 1.0441x over previous
//
#include <hip/hip_runtime.h>

#define LR 0.01f

// Problem constants (from reference setup_inputs): B=4, S=2048, D=1024, Ds=256
constexpr int Bc  = 4;
constexpr int Sc  = 2048;
constexpr int Dc  = 1024;
constexpr int Dsc = 256;

typedef unsigned short u16;
typedef __attribute__((ext_vector_type(8))) short bf16x8;
typedef __attribute__((ext_vector_type(4))) float f32x4;

__device__ __forceinline__ u16 f2bf(float f) {
  unsigned u = __float_as_uint(f);
  unsigned r = (u + 0x7fff + ((u >> 16) & 1)) >> 16;  // round-to-nearest-even
  return (u16)r;
}
__device__ __forceinline__ float bf2f(u16 h) {
  return __uint_as_float((unsigned)h << 16);
}

__device__ __forceinline__ void async_cp16(const void* g, void* l) {
  __builtin_amdgcn_global_load_lds(
      (const __attribute__((address_space(1))) unsigned int*)g,
      (__attribute__((address_space(3))) unsigned int*)l, 16, 0, 0);
}

// ---------------------------------------------------------------------------
// v21 = v19 (round-18 config) revert. v20's 8-wave/SIMD scan raised occupancy
// (38.7->74.2%) but grew total issued work ~18% (per-wave fixed overhead
// duplicated across 2x waves) -> net regression. The 4-wave/SIMD partition is
// the measured optimum of the TLP-vs-instruction-count trade
// (2/SIMD: 181us, 4/SIMD: 152.8us, 8/SIMD: 165us).
// ---------------------------------------------------------------------------

// Elementwise fp32 -> (hi, lo) bf16 split.
__global__ __launch_bounds__(256) void cast_split(const float* __restrict__ in,
                                                  u16* __restrict__ hi,
                                                  u16* __restrict__ lo) {
  int i = (blockIdx.x * 256 + threadIdx.x) * 4;
  float4 v = *(const float4*)&in[i];
  ushort4 h, l;
  h.x = f2bf(v.x); l.x = f2bf(v.x - bf2f(h.x));
  h.y = f2bf(v.y); l.y = f2bf(v.y - bf2f(h.y));
  h.z = f2bf(v.z); l.z = f2bf(v.z - bf2f(h.z));
  h.w = f2bf(v.w); l.w = f2bf(v.w - bf2f(h.w));
  *(ushort4*)&hi[i] = h;
  *(ushort4*)&lo[i] = l;
}

// W [K][N] fp32 -> WT [N][K] bf16 single (for Wu).
__global__ __launch_bounds__(256) void castT_bf16(const float* __restrict__ W,
                                                  u16* __restrict__ WT,
                                                  int K, int N) {
  __shared__ float t[32][33];
  const int bk = blockIdx.x * 32, bn = blockIdx.y * 32;
  const int tx = threadIdx.x & 31, ty = threadIdx.x >> 5;
  for (int r = ty; r < 32; r += 8) t[r][tx] = W[(size_t)(bk + r) * N + bn + tx];
  __syncthreads();
  for (int r = ty; r < 32; r += 8)
    WT[(size_t)(bn + r) * K + bk + tx] = f2bf(t[tx][r]);
}

// W [K][N] fp32 -> WT hi/lo [N][K] bf16 pair (for Wd).
__global__ __launch_bounds__(256) void castT_split(const float* __restrict__ W,
                                                   u16* __restrict__ WThi,
                                                   u16* __restrict__ WTlo,
                                                   int K, int N) {
  __shared__ float t[32][33];
  const int bk = blockIdx.x * 32, bn = blockIdx.y * 32;
  const int tx = threadIdx.x & 31, ty = threadIdx.x >> 5;
  for (int r = ty; r < 32; r += 8) t[r][tx] = W[(size_t)(bk + r) * N + bn + tx];
  __syncthreads();
  for (int r = ty; r < 32; r += 8) {
    float v = t[tx][r];
    u16 h = f2bf(v);
    WThi[(size_t)(bn + r) * K + bk + tx] = h;
    WTlo[(size_t)(bn + r) * K + bk + tx] = f2bf(v - bf2f(h));
  }
}

// ---------------------------------------------------------------------------
// 3-term split MFMA GEMM (verified): C = (Ah+Al)@(Bh+Bl) + bias.
// ---------------------------------------------------------------------------
__global__ __launch_bounds__(256) void gemm_bf16_split3(
    const u16* __restrict__ Ahi, const u16* __restrict__ Alo,
    const u16* __restrict__ BThi, const u16* __restrict__ BTlo,
    const float* __restrict__ bias, float* __restrict__ C,
    int M, int N, int K) {
  constexpr int BK = 32;
  __shared__ u16 sAh[2][64 * BK];
  __shared__ u16 sAl[2][64 * BK];
  __shared__ u16 sBh[2][64 * BK];
  __shared__ u16 sBl[2][64 * BK];

  const int wv = threadIdx.x >> 6, lane = threadIdx.x & 63;
  const int bm = blockIdx.x * 64, bn = blockIdx.y * 64;
  const int qm = (wv >> 1) * 32, qn = (wv & 1) * 32;
  const int lr = lane & 15, lk = lane >> 4;

  const int srow = lane >> 2;
  const int skp  = (lane & 3) * 8;
  const int NKS = K / BK;

#define GSTAGE(BUF, KS)                                                   \
  {                                                                       \
    async_cp16(Ahi + (size_t)(bm + wv * 16 + srow) * K + (KS)*BK + skp,   \
               &sAh[BUF][wv * 512]);                                      \
    async_cp16(Alo + (size_t)(bm + wv * 16 + srow) * K + (KS)*BK + skp,   \
               &sAl[BUF][wv * 512]);                                      \
    async_cp16(BThi + (size_t)(bn + wv * 16 + srow) * K + (KS)*BK + skp,  \
               &sBh[BUF][wv * 512]);                                      \
    async_cp16(BTlo + (size_t)(bn + wv * 16 + srow) * K + (KS)*BK + skp,  \
               &sBl[BUF][wv * 512]);                                      \
  }

  f32x4 acc00 = {0.f, 0.f, 0.f, 0.f}, acc01 = {0.f, 0.f, 0.f, 0.f};
  f32x4 acc10 = {0.f, 0.f, 0.f, 0.f}, acc11 = {0.f, 0.f, 0.f, 0.f};

  GSTAGE(0, 0);
  GSTAGE(1, 1);
  asm volatile("s_waitcnt vmcnt(4)" ::: "memory");
  __builtin_amdgcn_s_barrier();

  for (int ks = 0; ks < NKS; ++ks) {
    const int cb = ks & 1;
    bf16x8 ah0 = *(const bf16x8*)&sAh[cb][(qm + lr) * BK + lk * 8];
    bf16x8 ah1 = *(const bf16x8*)&sAh[cb][(qm + 16 + lr) * BK + lk * 8];
    bf16x8 al0 = *(const bf16x8*)&sAl[cb][(qm + lr) * BK + lk * 8];
    bf16x8 al1 = *(const bf16x8*)&sAl[cb][(qm + 16 + lr) * BK + lk * 8];
    bf16x8 bh0 = *(const bf16x8*)&sBh[cb][(qn + lr) * BK + lk * 8];
    bf16x8 bh1 = *(const bf16x8*)&sBh[cb][(qn + 16 + lr) * BK + lk * 8];
    bf16x8 bl0 = *(const bf16x8*)&sBl[cb][(qn + lr) * BK + lk * 8];
    bf16x8 bl1 = *(const bf16x8*)&sBl[cb][(qn + 16 + lr) * BK + lk * 8];
    acc00 = __builtin_amdgcn_mfma_f32_16x16x32_bf16(ah0, bh0, acc00, 0, 0, 0);
    acc01 = __builtin_amdgcn_mfma_f32_16x16x32_bf16(ah0, bh1, acc01, 0, 0, 0);
    acc10 = __builtin_amdgcn_mfma_f32_16x16x32_bf16(ah1, bh0, acc10, 0, 0, 0);
    acc11 = __builtin_amdgcn_mfma_f32_16x16x32_bf16(ah1, bh1, acc11, 0, 0, 0);
    acc00 = __builtin_amdgcn_mfma_f32_16x16x32_bf16(ah0, bl0, acc00, 0, 0, 0);
    acc01 = __builtin_amdgcn_mfma_f32_16x16x32_bf16(ah0, bl1, acc01, 0, 0, 0);
    acc10 = __builtin_amdgcn_mfma_f32_16x16x32_bf16(ah1, bl0, acc10, 0, 0, 0);
    acc11 = __builtin_amdgcn_mfma_f32_16x16x32_bf16(ah1, bl1, acc11, 0, 0, 0);
    acc00 = __builtin_amdgcn_mfma_f32_16x16x32_bf16(al0, bh0, acc00, 0, 0, 0);
    acc01 = __builtin_amdgcn_mfma_f32_16x16x32_bf16(al0, bh1, acc01, 0, 0, 0);
    acc10 = __builtin_amdgcn_mfma_f32_16x16x32_bf16(al1, bh0, acc10, 0, 0, 0);
    acc11 = __builtin_amdgcn_mfma_f32_16x16x32_bf16(al1, bh1, acc11, 0, 0, 0);
    __builtin_amdgcn_s_barrier();
    if (ks + 2 < NKS) {
      GSTAGE(cb, ks + 2);
      asm volatile("s_waitcnt vmcnt(4)" ::: "memory");
    } else {
      asm volatile("s_waitcnt vmcnt(0)" ::: "memory");
    }
    __builtin_amdgcn_s_barrier();
  }

#define WRT(ACC, AR, BC)                                                 \
  {                                                                      \
    _Pragma("unroll")                                                    \
    for (int r = 0; r < 4; ++r) {                                        \
      int row = bm + qm + (AR) + lk * 4 + r;                             \
      int col = bn + qn + (BC) + lr;                                     \
      C[(size_t)row * N + col] = ACC[r] + bias[col];                     \
    }                                                                    \
  }
  WRT(acc00, 0, 0) WRT(acc01, 0, 16) WRT(acc10, 16, 0) WRT(acc11, 16, 16)
#undef WRT
#undef GSTAGE
}

// ---------------------------------------------------------------------------
// bf16 MFMA GEMM with HI/LO-split A only (verified).
// ---------------------------------------------------------------------------
__global__ __launch_bounds__(256) void gemm_bf16_split(
    const u16* __restrict__ Ahi, const u16* __restrict__ Alo,
    const u16* __restrict__ BT, const float* __restrict__ bias,
    const float* __restrict__ resid, float* __restrict__ C,
    int M, int N, int K) {
  constexpr int BK = 32;
  __shared__ u16 sAh[2][64 * BK];
  __shared__ u16 sAl[2][64 * BK];
  __shared__ u16 sB[2][64 * BK];

  const int wv = threadIdx.x >> 6, lane = threadIdx.x & 63;
  const int bm = blockIdx.x * 64, bn = blockIdx.y * 64;
  const int qm = (wv >> 1) * 32, qn = (wv & 1) * 32;
  const int lr = lane & 15, lk = lane >> 4;

  const int srow = lane >> 2;
  const int skp  = (lane & 3) * 8;
  const int NKS = K / BK;

#define GSTAGE(BUF, KS)                                                   \
  {                                                                       \
    async_cp16(Ahi + (size_t)(bm + wv * 16 + srow) * K + (KS)*BK + skp,   \
               &sAh[BUF][wv * 512]);                                      \
    async_cp16(Alo + (size_t)(bm + wv * 16 + srow) * K + (KS)*BK + skp,   \
               &sAl[BUF][wv * 512]);                                      \
    async_cp16(BT + (size_t)(bn + wv * 16 + srow) * K + (KS)*BK + skp,    \
               &sB[BUF][wv * 512]);                                       \
  }

  f32x4 acc00 = {0.f, 0.f, 0.f, 0.f}, acc01 = {0.f, 0.f, 0.f, 0.f};
  f32x4 acc10 = {0.f, 0.f, 0.f, 0.f}, acc11 = {0.f, 0.f, 0.f, 0.f};

  GSTAGE(0, 0);
  GSTAGE(1, 1);
  asm volatile("s_waitcnt vmcnt(3)" ::: "memory");
  __builtin_amdgcn_s_barrier();

  for (int ks = 0; ks < NKS; ++ks) {
    const int cb = ks & 1;
    bf16x8 ah0 = *(const bf16x8*)&sAh[cb][(qm + lr) * BK + lk * 8];
    bf16x8 ah1 = *(const bf16x8*)&sAh[cb][(qm + 16 + lr) * BK + lk * 8];
    bf16x8 al0 = *(const bf16x8*)&sAl[cb][(qm + lr) * BK + lk * 8];
    bf16x8 al1 = *(const bf16x8*)&sAl[cb][(qm + 16 + lr) * BK + lk * 8];
    bf16x8 b0  = *(const bf16x8*)&sB[cb][(qn + lr) * BK + lk * 8];
    bf16x8 b1  = *(const bf16x8*)&sB[cb][(qn + 16 + lr) * BK + lk * 8];
    acc00 = __builtin_amdgcn_mfma_f32_16x16x32_bf16(ah0, b0, acc00, 0, 0, 0);
    acc01 = __builtin_amdgcn_mfma_f32_16x16x32_bf16(ah0, b1, acc01, 0, 0, 0);
    acc10 = __builtin_amdgcn_mfma_f32_16x16x32_bf16(ah1, b0, acc10, 0, 0, 0);
    acc11 = __builtin_amdgcn_mfma_f32_16x16x32_bf16(ah1, b1, acc11, 0, 0, 0);
    acc00 = __builtin_amdgcn_mfma_f32_16x16x32_bf16(al0, b0, acc00, 0, 0, 0);
    acc01 = __builtin_amdgcn_mfma_f32_16x16x32_bf16(al0, b1, acc01, 0, 0, 0);
    acc10 = __builtin_amdgcn_mfma_f32_16x16x32_bf16(al1, b0, acc10, 0, 0, 0);
    acc11 = __builtin_amdgcn_mfma_f32_16x16x32_bf16(al1, b1, acc11, 0, 0, 0);
    __builtin_amdgcn_s_barrier();
    if (ks + 2 < NKS) {
      GSTAGE(cb, ks + 2);
      asm volatile("s_waitcnt vmcnt(3)" ::: "memory");
    } else {
      asm volatile("s_waitcnt vmcnt(0)" ::: "memory");
    }
    __builtin_amdgcn_s_barrier();
  }

#define WRT(ACC, AR, BC)                                                 \
  {                                                                      \
    _Pragma("unroll")                                                    \
    for (int r = 0; r < 4; ++r) {                                        \
      int row = bm + qm + (AR) + lk * 4 + r;                             \
      int col = bn + qn + (BC) + lr;                                     \
      float v = ACC[r] + bias[col];                                      \
      if (resid) v += resid[(size_t)row * N + col];                      \
      C[(size_t)row * N + col] = v;                                      \
    }                                                                    \
  }
  WRT(acc00, 0, 0) WRT(acc01, 0, 16) WRT(acc10, 16, 0) WRT(acc11, 16, 16)
#undef WRT
#undef GSTAGE
}

// ---------------------------------------------------------------------------
// Scan support.
// ---------------------------------------------------------------------------

template <int CTRL, int RM>
__device__ __forceinline__ float dpp_sum(float v) {
  int moved = __builtin_amdgcn_update_dpp(0, __float_as_int(v), CTRL, RM, 0xF, false);
  return v + __int_as_float(moved);
}

__device__ __forceinline__ float rdlane(float v, int l) {
  return __int_as_float(__builtin_amdgcn_readlane(__float_as_int(v), l));
}

constexpr int RCH = 32;        // rows per chunk
constexpr int NCH = Sc / RCH;  // 64 chunks

// MTg[bc][s*32+t] = M[t][s], M = (I + L)^{-1}, L[t][s] = LR*dot(f_t,f_s) s<t
__global__ __launch_bounds__(256) void gram_inv(const float* __restrict__ feat,
                                                float* __restrict__ MTg) {
  const int bc = blockIdx.x;  // 0..B*NCH-1
  __shared__ float Fl[32 * 260];
  __shared__ float Gl[32 * 32];
  __shared__ float Ml[32 * 32];
  const float* src = feat + (size_t)bc * RCH * Dsc;
  for (int i = threadIdx.x; i < 32 * 256; i += 256) {
    int r = i >> 8, cc = i & 255;
    Fl[r * 260 + cc] = src[i];
  }
  __syncthreads();
#pragma unroll
  for (int k2 = 0; k2 < 4; ++k2) {
    int idx = threadIdx.x + (k2 << 8);
    int t = idx >> 5, s = idx & 31;
    float sum = 0.f;
    if (s < t) {
      const float4* ft = (const float4*)&Fl[t * 260];
      const float4* fs = (const float4*)&Fl[s * 260];
#pragma unroll
      for (int i = 0; i < 64; ++i) {
        float4 a = ft[i], b = fs[i];
        sum = fmaf(a.x, b.x, sum); sum = fmaf(a.y, b.y, sum);
        sum = fmaf(a.z, b.z, sum); sum = fmaf(a.w, b.w, sum);
      }
      sum *= LR;
    }
    Gl[idx] = sum;
  }
  __syncthreads();
  if (threadIdx.x < 32) {
    const int s = threadIdx.x;
    for (int t = 0; t < 32; ++t) {
      float sum = 0.f;
      for (int u = 0; u < t; ++u)
        sum = fmaf(Gl[t * 32 + u], Ml[u * 32 + s], sum);
      Ml[t * 32 + s] = ((t == s) ? 1.f : 0.f) - sum;
    }
  }
  __syncthreads();
  float* dst = MTg + (size_t)bc * 1024;
#pragma unroll
  for (int k2 = 0; k2 < 4; ++k2) {
    int idx = threadIdx.x + (k2 << 8);
    int s = idx >> 5, t = idx & 31;
    dst[idx] = Ml[t * 32 + s];  // transposed store
  }
}

__device__ __forceinline__ void async_copy16f(const float* g, float* l) {
  __builtin_amdgcn_global_load_lds(
      (const __attribute__((address_space(1))) unsigned int*)g,
      (__attribute__((address_space(3))) unsigned int*)l, 16, 0, 0);
}

// Per-wave local rows 0..7.
#define QROWS(X) X(0) X(1) X(2) X(3) X(4) X(5) X(6) X(7)

// ---------------------------------------------------------------------------
// Scan (v16 partition, verified @152.8us): 512 blocks x 8 waves (2 cols x
// 4 row-quarters, 8 rows/wave); LDS 76KB -> 2 blocks/CU -> 4 waves/SIMD.
// w' = w - e_j state (no FJ on hot path); M in registers (prefetched).
// ---------------------------------------------------------------------------
__global__ __launch_bounds__(512, 4) void ttt_scan(
    const float* __restrict__ feat, const float* __restrict__ MTg,
    u16* __restrict__ predsHi, u16* __restrict__ predsLo) {
  const int lane = threadIdx.x & 63;
  const int wv   = threadIdx.x >> 6;   // 0..7
  const int lm   = lane & 31;
  const int cl   = wv & 1;             // column within block
  const int qr   = wv >> 1;            // row quarter (8 rows each)
  const int rbase = qr << 3;

  // XCD-locality swizzle for 512 blocks (bijective).
  const int bi  = blockIdx.x;                    // 0..511
  const int xcd = bi & 7;
  const int b   = xcd >> 1;                      // 0..3
  const int q   = ((bi >> 3) << 1) | (xcd & 1);  // 0..127 col-pair within b
  const int j   = (q << 1) | cl;                 // 0..255

  __shared__ float  ldsF[2][RCH * Dsc];  // 64 KB
  __shared__ float  ldsE[2][4][64];      // 2 KB  e-partial exchange
  __shared__ float4 ldsA[2][4][64];      // 8 KB  acc partials (qr 1..3 used)
  __shared__ float4 ldsW[2][64];         // 2 KB  w' publish (qr0 -> others)

  const float* fb0 = feat + (size_t)b * Sc * Dsc;
  const float* Mg  = MTg + (size_t)b * NCH * 1024;
  u16* pbh = predsHi + (size_t)b * Sc * Dsc + j;
  u16* pbl = predsLo + (size_t)b * Sc * Dsc + j;

#define STAGE(BUF, C0)                                                     \
  {                                                                        \
    _Pragma("unroll")                                                      \
    for (int r_ = 0; r_ < 4; ++r_) {                                       \
      const int row_ = (wv << 2) | r_;                                     \
      async_copy16f(fb0 + (size_t)((C0) * RCH + row_) * Dsc + (lane << 2), \
                    &ldsF[BUF][row_ * Dsc]);                               \
    }                                                                      \
  }

#define LOADM(C1)                                             \
  {                                                           \
    const float* mp_ = Mg + (size_t)(C1) * 1024 + lm;         \
    Mn0 = mp_[(rbase + 0) * 32]; Mn1 = mp_[(rbase + 1) * 32]; \
    Mn2 = mp_[(rbase + 2) * 32]; Mn3 = mp_[(rbase + 3) * 32]; \
    Mn4 = mp_[(rbase + 4) * 32]; Mn5 = mp_[(rbase + 5) * 32]; \
    Mn6 = mp_[(rbase + 6) * 32]; Mn7 = mp_[(rbase + 7) * 32]; \
  }

#define DECLF(R) float4 F4_##R;
#define DECLD(R) float dsc_##R;

#define LOADF(R) F4_##R = *(const float4*)&pF2[(R) * 256 + (lane << 2)];

#define P0C(R)                                                                 \
  {                                                                            \
    float dd = fmaf(F4_##R.y, w4y, F4_##R.x * w4x) +                           \
               fmaf(F4_##R.w, w4w, F4_##R.z * w4z);                            \
    dd = dpp_sum<0x111, 0xF>(dd);                                              \
    dd = dpp_sum<0x112, 0xF>(dd);                                              \
    dd = dpp_sum<0x114, 0xF>(dd);                                              \
    dd = dpp_sum<0x118, 0xF>(dd);                                              \
    dd = dpp_sum<0x142, 0xA>(dd);                                              \
    dd = dpp_sum<0x143, 0xC>(dd);                                              \
    dsc_##R = rdlane(dd, 63);                                                  \
  }

#define MV(R) e_p = fmaf(Mc##R, dsc_##R, e_p);

#define ACCT(R)                                    \
  {                                                \
    float et_ = rdlane(v_e, rbase + (R));          \
    accx = fmaf(et_, F4_##R.x, accx);              \
    accy = fmaf(et_, F4_##R.y, accy);              \
    accz = fmaf(et_, F4_##R.z, accz);              \
    accw = fmaf(et_, F4_##R.w, accw);              \
  }

  float Mc0, Mc1, Mc2, Mc3, Mc4, Mc5, Mc6, Mc7;
  float Mn0, Mn1, Mn2, Mn3, Mn4, Mn5, Mn6, Mn7;

  STAGE(0, 0);
  STAGE(1, 1);
  LOADM(0);
  Mc0 = Mn0; Mc1 = Mn1; Mc2 = Mn2; Mc3 = Mn3;
  Mc4 = Mn4; Mc5 = Mn5; Mc6 = Mn6; Mc7 = Mn7;
  asm volatile("s_waitcnt vmcnt(12)" ::: "memory");
  __builtin_amdgcn_s_barrier();
  __builtin_amdgcn_sched_barrier(0);

  // w' = w - e_j state: init -e_j (component j&3 of lane j>>2).
  const int jl4 = j >> 2, jc = j & 3;
  float w4x = (lane == jl4 && jc == 0) ? -1.f : 0.f;
  float w4y = (lane == jl4 && jc == 1) ? -1.f : 0.f;
  float w4z = (lane == jl4 && jc == 2) ? -1.f : 0.f;
  float w4w = (lane == jl4 && jc == 3) ? -1.f : 0.f;

#pragma unroll 1
  for (int c = 0; c < NCH; ++c) {
    const int cb = c & 1;
    const float* pF  = &ldsF[cb][0];
    const float* pF2 = pF + (rbase << 8);

    if (c + 1 < NCH) LOADM(c + 1);

    QROWS(DECLF)
    QROWS(DECLD)
    float e_p = 0.f;
    float accx = 0.f, accy = 0.f, accz = 0.f, accw = 0.f;

    float v_fjcol = 0.f;
    if (qr == 0) v_fjcol = pF[lm * 256 + j];

    QROWS(LOADF)
    __builtin_amdgcn_sched_barrier(0);
    QROWS(P0C)

    MV(0) MV(1) MV(2) MV(3) MV(4) MV(5) MV(6) MV(7)

    ldsE[cl][qr][lane] = e_p;
    __builtin_amdgcn_s_barrier();                 // bE
    float v_e = (ldsE[cl][0][lane] + ldsE[cl][1][lane]) +
                (ldsE[cl][2][lane] + ldsE[cl][3][lane]);

    if (qr == 0 && lane < 32) {
      float v = v_e + v_fjcol;
      u16 hi = f2bf(v);
      u16 lo = f2bf(v - bf2f(hi));
      pbh[(size_t)(c * RCH + lane) * Dsc] = hi;
      pbl[(size_t)(c * RCH + lane) * Dsc] = lo;
    }

    QROWS(ACCT)

    if (qr != 0) ldsA[cl][qr][lane] = make_float4(accx, accy, accz, accw);
    __builtin_amdgcn_s_barrier();                 // bA
    if (qr == 0) {
      float4 a1 = ldsA[cl][1][lane], a2 = ldsA[cl][2][lane],
             a3 = ldsA[cl][3][lane];
      accx += a1.x + a2.x + a3.x; accy += a1.y + a2.y + a3.y;
      accz += a1.z + a2.z + a3.z; accw += a1.w + a2.w + a3.w;
      w4x = fmaf(-LR, accx, w4x); w4y = fmaf(-LR, accy, w4y);
      w4z = fmaf(-LR, accz, w4z); w4w = fmaf(-LR, accw, w4w);
      ldsW[cl][lane] = make_float4(w4x, w4y, w4z, w4w);
    }

    if (c + 2 < NCH) {
      STAGE(cb, c + 2);
      asm volatile("s_waitcnt vmcnt(12)" ::: "memory");
    } else {
      asm volatile("s_waitcnt vmcnt(0)" ::: "memory");
    }
    __builtin_amdgcn_s_barrier();                 // bFinal
    if (qr != 0) {
      float4 wp = ldsW[cl][lane];
      w4x = wp.x; w4y = wp.y; w4z = wp.z; w4w = wp.w;
    }
    Mc0 = Mn0; Mc1 = Mn1; Mc2 = Mn2; Mc3 = Mn3;
    Mc4 = Mn4; Mc5 = Mn5; Mc6 = Mn6; Mc7 = Mn7;
    __builtin_amdgcn_sched_barrier(0);
  }
#undef ACCT
#undef MV
#undef P0C
#undef LOADF
#undef DECLD
#undef DECLF
#undef LOADM
#undef STAGE
}

extern "C" void kernel_launch(void* const* d_in, const int* in_sizes, int n_in,
                              void* d_out, int out_size, void* d_ws, size_t ws_size,
                              hipStream_t stream) {
  const float* x  = (const float*)d_in[0];  // (B,S,D)
  const float* Wd = (const float*)d_in[1];  // (D,Ds)
  const float* bd = (const float*)d_in[2];  // (Ds)
  const float* Wu = (const float*)d_in[3];  // (Ds,D)
  const float* bu = (const float*)d_in[4];  // (D)
  float* out = (float*)d_out;               // (B,S,D)

  const int M = Bc * Sc;  // 8192

  // Workspace layout (~43.5 MB with aliasing):
  u16*   xhi   = (u16*)d_ws;                         // 16.8 MB
  u16*   xlo   = xhi + (size_t)M * Dc;               // 16.8 MB
  float* feat  = (float*)(xlo + (size_t)M * Dc);     // 8.4 MB
  u16*   wdThi = (u16*)(feat + (size_t)M * Dsc);     // 0.5 MB [Ds][D]
  u16*   wdTlo = wdThi + (size_t)Dc * Dsc;           // 0.5 MB
  u16*   wuT   = wdTlo + (size_t)Dc * Dsc;           // 0.5 MB [D][Ds]
  // Aliased into xhi's region (xhi/xlo dead after gemm1; stream-ordered):
  float* MTg     = (float*)xhi;                      // 1 MB
  u16*   predsHi = (u16*)(MTg + (size_t)Bc * NCH * 1024);  // 4.2 MB
  u16*   predsLo = predsHi + (size_t)Bc * Sc * Dsc;        // 4.2 MB

  // Casts: x -> hi/lo bf16; Wd -> transposed hi/lo; Wu -> transposed bf16.
  cast_split<<<dim3(M * Dc / 1024), dim3(256), 0, stream>>>(x, xhi, xlo);
  castT_split<<<dim3(Dc / 32, Dsc / 32), dim3(256), 0, stream>>>(
      Wd, wdThi, wdTlo, Dc, Dsc);
  castT_bf16<<<dim3(Dsc / 32, Dc / 32), dim3(256), 0, stream>>>(
      Wu, wuT, Dsc, Dc);

  // feat = (xhi+xlo) @ (wdhi+wdlo) + b_down  (3-term MFMA; rel err ~1e-5)
  gemm_bf16_split3<<<dim3(M / 64, Dsc / 64), dim3(256), 0, stream>>>(
      xhi, xlo, wdThi, wdTlo, bd, feat, M, Dsc, Dc);

  // per-chunk M = (I+L)^{-1} (fp32, parallel)
  gram_inv<<<dim3(Bc * NCH), dim3(256), 0, stream>>>(feat, MTg);

  // chunked scan -> preds hi/lo bf16 (512 blocks x 8 waves; 4 waves/SIMD)
  ttt_scan<<<dim3(Bc * Dsc / 2), dim3(512), 0, stream>>>(
      feat, MTg, predsHi, predsLo);

  // out = (predsHi+predsLo) @ W_up + b_up + x  (MFMA bf16)
  gemm_bf16_split<<<dim3(M / 64, Dc / 64), dim3(256), 0, stream>>>(
      predsHi, predsLo, wuT, bu, x, out, M, Dc, Dsc);
}